// Round 6
// baseline (1143.541 us; speedup 1.0000x reference)
//
#include <hip/hip_runtime.h>

// Problem constants (from reference)
#define PP 712740      // M*K points
#define MM 35637       // M
#define KK 20          // K neighbors
#define NF 15872       // N points in x_feat
#define NT64 11137     // ceil(PP/64) point-tiles of 64
#define NTILES 44547   // ceil(PP/16) (k_logits tiling)
// FEAT = 128 channels, W0 = 1.0, EPS = 1e-5

typedef _Float16 h16;
typedef __attribute__((ext_vector_type(8))) _Float16 f16x8;
typedef __attribute__((ext_vector_type(4))) _Float16 f16x4;
typedef __attribute__((ext_vector_type(4))) float f32x4;

// ---------------------------------------------------------------------------
// Zero the stats accumulators (8 layers x 256 doubles).
// ---------------------------------------------------------------------------
__global__ __launch_bounds__(256) void k_zero(double* __restrict__ gs) {
  const int t = threadIdx.x;
#pragma unroll
  for (int i = 0; i < 8; ++i) gs[i * 256 + t] = 0.0;
}

// ---------------------------------------------------------------------------
// Layer 0 (K=7, VALU), strip version: blockIdx.y = ks owns channels
// [ks*32, ks*32+32). Lane (q,ln): point p=tile*16+ln, channels ks*32+q*8+j.
// ---------------------------------------------------------------------------
__global__ __launch_bounds__(256, 4) void k_layer0(
    const float* __restrict__ up,    // [7][PP]
    const float* __restrict__ w0,    // [128][7]
    h16* __restrict__ z,             // [NT64*64][128] (padded)
    double* __restrict__ gs)         // [256]: sum[128], sumsq[128]
{
  __shared__ double red[4][64];
  const int t = threadIdx.x;
  const int w = t >> 6;
  const int lane = t & 63;
  const int ln = lane & 15;
  const int q = lane >> 4;
  const int ks = blockIdx.y;         // channel strip

  float wr[8][7];
#pragma unroll
  for (int j = 0; j < 8; ++j) {
    const int c = ks * 32 + q * 8 + j;
#pragma unroll
    for (int c7 = 0; c7 < 7; ++c7) wr[j][c7] = w0[c * 7 + c7];
  }

  float sp[8], qp[8];
#pragma unroll
  for (int j = 0; j < 8; ++j) { sp[j] = 0.f; qp[j] = 0.f; }

  for (int tile = blockIdx.x * 4 + w; tile < NTILES; tile += gridDim.x * 4) {
    const int p = tile * 16 + ln;
    const bool act = p < PP;
    float u[7];
#pragma unroll
    for (int c7 = 0; c7 < 7; ++c7) u[c7] = act ? up[c7 * PP + p] : 0.f;

    f16x8 o;
#pragma unroll
    for (int j = 0; j < 8; ++j) {
      float acc = 0.f;
#pragma unroll
      for (int c7 = 0; c7 < 7; ++c7) acc = fmaf(wr[j][c7], u[c7], acc);
      o[j] = (h16)acc;
      sp[j] += acc;
      qp[j] = fmaf(acc, acc, qp[j]);
    }
    if (act) *(f16x8*)(z + (size_t)p * 128 + ks * 32 + q * 8) = o;
  }

#pragma unroll
  for (int j = 0; j < 8; ++j) {
#pragma unroll
    for (int d = 1; d < 16; d <<= 1) {
      sp[j] += __shfl_xor(sp[j], d, 64);
      qp[j] += __shfl_xor(qp[j], d, 64);
    }
  }
  if (ln == 0) {
#pragma unroll
    for (int j = 0; j < 8; ++j) {
      red[w][q * 8 + j] = (double)sp[j];
      red[w][32 + q * 8 + j] = (double)qp[j];
    }
  }
  __syncthreads();
  if (t < 64) {
    const double v = red[0][t] + red[1][t] + red[2][t] + red[3][t];
    const int c = ks * 32 + (t & 31);
    atomicAdd(&gs[(t >> 5) * 128 + c], v);
  }
}

// ---------------------------------------------------------------------------
// Middle layer (x7), block-cooperative MFMA:
//  - Block tile = 64 points. Staging: each thread BN+sines its 8 fixed
//    channels x 4 points, writes f16x8 frag-slots to LDS (lane-contiguous,
//    conflict-free). Double-buffered, ONE __syncthreads per tile.
//  - Wave w computes output channels [w*32, w*32+32): W-frags 32 VGPR,
//    acc 8. MFMA operands SWAPPED: D[o][p] -> per lane 4 consecutive
//    channels @ 1 point -> direct 8B global stores (no LDS transpose).
//  - Stats from acc regs: 16 fp32 accumulators, butterfly at end, f64 atomics.
// ---------------------------------------------------------------------------
__global__ __launch_bounds__(256, 3) void k_layer(
    h16* __restrict__ z,              // [NT64*64][128], in-place
    const double* __restrict__ gsp,   // stats of previous layer output
    double* __restrict__ gso,         // stats of this layer output
    const float* __restrict__ W,      // [128][128] fp32
    const float* __restrict__ gamma,  // [128]
    const float* __restrict__ beta)   // [128]
{
  __shared__ h16 stage[2][16 * 64 * 8];  // [buf][(st*4+ks)*64 + lane][8]
  const int t = threadIdx.x;
  const int w = t >> 6;
  const int lane = t & 63;
  const int ln = lane & 15;
  const int q = lane >> 4;

  // BN constants for this thread's 8 fixed channels: c = w*32 + q*8 + j
  float sc[8], sh[8];
#pragma unroll
  for (int j = 0; j < 8; ++j) {
    const int c = w * 32 + q * 8 + j;
    const double n = (double)PP;
    const double mu = gsp[c] / n;
    const double var = gsp[128 + c] / n - mu * mu;
    const float rstd = (float)(1.0 / sqrt(var + 1e-5));
    sc[j] = rstd * gamma[c];
    sh[j] = beta[c] - (float)mu * sc[j];
  }

  // Persistent W fragments (A-operand): rows o = w*32 + nt*16 + ln
  f16x8 bfr[2][4];
#pragma unroll
  for (int nt = 0; nt < 2; ++nt) {
    const float* wrow = W + (size_t)(w * 32 + nt * 16 + ln) * 128;
#pragma unroll
    for (int ks = 0; ks < 4; ++ks) {
      const float* src = wrow + ks * 32 + q * 8;
      const float4 aa = *(const float4*)src;
      const float4 bb = *(const float4*)(src + 4);
      f16x8 b;
      b[0] = (h16)aa.x; b[1] = (h16)aa.y; b[2] = (h16)aa.z; b[3] = (h16)aa.w;
      b[4] = (h16)bb.x; b[5] = (h16)bb.y; b[6] = (h16)bb.z; b[7] = (h16)bb.w;
      bfr[nt][ks] = b;
    }
  }

  float sp[8], qp[8];
#pragma unroll
  for (int i = 0; i < 8; ++i) { sp[i] = 0.f; qp[i] = 0.f; }

  const int G = gridDim.x;
  int tile = blockIdx.x;
  int buf = 0;

  // initial prefetch: wave loads ALL 64 points of its channel slice
  f16x8 raw[4];
#pragma unroll
  for (int st = 0; st < 4; ++st)
    raw[st] = *(const f16x8*)(z + (size_t)(tile * 64 + st * 16 + ln) * 128 +
                              w * 32 + q * 8);

  while (tile < NT64) {
    // ---- stage: BN + sine -> LDS frag-slots (slot id = st*4 + w) ----
#pragma unroll
    for (int st = 0; st < 4; ++st) {
      const int p = tile * 64 + st * 16 + ln;
      const bool act = p < PP;
      f16x8 a;
#pragma unroll
      for (int j = 0; j < 8; ++j) {
        const float h = fmaf((float)raw[st][j], sc[j], sh[j]);
        a[j] = act ? (h16)__sinf(h) : (h16)0.f;
      }
      *(f16x8*)&stage[buf][((st * 4 + w) * 64 + lane) * 8] = a;
    }

    // ---- prefetch next tile (same block owns tile+G; pad rows safe) ----
    const int nxt = tile + G;
    const int npf = (nxt < NT64) ? nxt : tile;
#pragma unroll
    for (int st = 0; st < 4; ++st)
      raw[st] = *(const f16x8*)(z + (size_t)(npf * 64 + st * 16 + ln) * 128 +
                                w * 32 + q * 8);

    __syncthreads();

    // ---- MFMA phase: D[o][p] = sum_c W[o][c] * act[p][c] ----
#pragma unroll
    for (int st = 0; st < 4; ++st) {
      f16x8 bf[4];
#pragma unroll
      for (int ks = 0; ks < 4; ++ks)
        bf[ks] = *(const f16x8*)&stage[buf][((st * 4 + ks) * 64 + lane) * 8];

      f32x4 acc0 = (f32x4){0.f, 0.f, 0.f, 0.f};
      f32x4 acc1 = (f32x4){0.f, 0.f, 0.f, 0.f};
#pragma unroll
      for (int ks = 0; ks < 4; ++ks) {
        acc0 = __builtin_amdgcn_mfma_f32_16x16x32_f16(bfr[0][ks], bf[ks], acc0, 0, 0, 0);
        acc1 = __builtin_amdgcn_mfma_f32_16x16x32_f16(bfr[1][ks], bf[ks], acc1, 0, 0, 0);
      }

      const int p = tile * 64 + st * 16 + ln;
      const bool act = p < PP;
      // nt = 0
      {
        f16x4 v;
#pragma unroll
        for (int r = 0; r < 4; ++r) {
          const float d = acc0[r];
          sp[r] += d; qp[r] = fmaf(d, d, qp[r]);
          v[r] = (h16)d;
        }
        if (act) *(f16x4*)(z + (size_t)p * 128 + w * 32 + q * 4) = v;
      }
      // nt = 1
      {
        f16x4 v;
#pragma unroll
        for (int r = 0; r < 4; ++r) {
          const float d = acc1[r];
          sp[4 + r] += d; qp[4 + r] = fmaf(d, d, qp[4 + r]);
          v[r] = (h16)d;
        }
        if (act) *(f16x4*)(z + (size_t)p * 128 + w * 32 + 16 + q * 4) = v;
      }
    }

    tile = nxt;
    buf ^= 1;
  }

  // ---- stats: reduce over the 16 ln-lanes, then f64 atomics ----
#pragma unroll
  for (int s = 0; s < 8; ++s) {
#pragma unroll
    for (int d = 1; d < 16; d <<= 1) {
      sp[s] += __shfl_xor(sp[s], d, 64);
      qp[s] += __shfl_xor(qp[s], d, 64);
    }
  }
  if (ln == 0) {
#pragma unroll
    for (int nt = 0; nt < 2; ++nt)
#pragma unroll
      for (int r = 0; r < 4; ++r) {
        const int c = w * 32 + nt * 16 + q * 4 + r;
        atomicAdd(&gso[c], (double)sp[nt * 4 + r]);
        atomicAdd(&gso[128 + c], (double)qp[nt * 4 + r]);
      }
  }
}

// ---------------------------------------------------------------------------
// Final conv (128->1) with BN7+sine, z point-major.
// ---------------------------------------------------------------------------
__global__ __launch_bounds__(256) void k_logits(
    const h16* __restrict__ z,
    const double* __restrict__ gsp,
    const float* __restrict__ gamma,
    const float* __restrict__ beta,
    const float* __restrict__ fw,
    const float* __restrict__ fb,
    float* __restrict__ logits)
{
  __shared__ float sc_s[128], sh_s[128], fws[128];
  const int t = threadIdx.x;
  if (t < 128) {
    const double n = (double)PP;
    const double mu = gsp[t] / n;
    const double var = gsp[128 + t] / n - mu * mu;
    const float rstd = (float)(1.0 / sqrt(var + 1e-5));
    const float sc = rstd * gamma[t];
    sc_s[t] = sc;
    sh_s[t] = beta[t] - (float)mu * sc;
    fws[t] = fw[t];
  }
  __syncthreads();

  const int w = t >> 6;
  const int lane = t & 63;
  const int ln = lane & 15;
  const int q = lane >> 4;
  const float fbv = fb[0];

  const int gw = blockIdx.x * 4 + w;
  for (int tile = gw; tile < NTILES; tile += gridDim.x * 4) {
    const int p = tile * 16 + ln;
    float part = 0.f;
    if (p < PP) {
#pragma unroll
      for (int ks = 0; ks < 4; ++ks) {
        const f16x8 raw = *(const f16x8*)(z + (size_t)p * 128 + ks * 32 + q * 8);
#pragma unroll
        for (int j = 0; j < 8; ++j) {
          const int c = ks * 32 + q * 8 + j;
          part = fmaf(fws[c], __sinf(fmaf((float)raw[j], sc_s[c], sh_s[c])), part);
        }
      }
    }
    part += __shfl_xor(part, 16, 64);
    part += __shfl_xor(part, 32, 64);
    if (q == 0 && p < PP) logits[p] = part + fbv;
  }
}

// ---------------------------------------------------------------------------
// Softmax over K=20 per m + gather-weighted sum of x_feat rows. 1 wave per m.
// ---------------------------------------------------------------------------
__global__ __launch_bounds__(256) void k_out(
    const float* __restrict__ logits,  // [PP]
    const int* __restrict__ idx,       // [MM][KK]
    const float* __restrict__ xf,      // [NF][128]
    float* __restrict__ out)           // [MM][128]
{
  const int gw = (int)((blockIdx.x * 256 + threadIdx.x) >> 6);
  const int lane = threadIdx.x & 63;
  if (gw >= MM) return;
  const int m = gw;

  float l[KK];
#pragma unroll
  for (int k = 0; k < KK; ++k) l[k] = logits[m * KK + k];
  float mx = l[0];
#pragma unroll
  for (int k = 1; k < KK; ++k) mx = fmaxf(mx, l[k]);
  float ssum = 0.f;
#pragma unroll
  for (int k = 0; k < KK; ++k) { l[k] = __expf(l[k] - mx); ssum += l[k]; }
  const float inv = 1.f / ssum;

  float a0 = 0.f, a1 = 0.f;
#pragma unroll
  for (int k = 0; k < KK; ++k) {
    const int r = idx[m * KK + k];
    const float wk = l[k] * inv;
    a0 = fmaf(wk, xf[r * 128 + lane], a0);
    a1 = fmaf(wk, xf[r * 128 + 64 + lane], a1);
  }
  out[m * 128 + lane] = a0;
  out[m * 128 + 64 + lane] = a1;
}

// ---------------------------------------------------------------------------
// Fallback (small workspace): recompute chain in registers per point.
// ---------------------------------------------------------------------------
__global__ __launch_bounds__(256) void k_chain(
    const float* __restrict__ up,
    const float* __restrict__ w0,
    const float* __restrict__ wc,
    const float* __restrict__ gam,
    const float* __restrict__ bet,
    const double* __restrict__ gs,
    double* __restrict__ gso,
    int jl, int mode,
    const float* __restrict__ fw,
    const float* __restrict__ fb,
    float* __restrict__ logits)
{
  __shared__ float sc_s[8][128], sh_s[8][128];
  __shared__ double bred[4][256];
  const int t = threadIdx.x;
  const int lane = t & 63;

  const int nbn = (mode == 0) ? jl : 8;
  for (int i = t; i < nbn * 128; i += 256) {
    const int L = i >> 7, c = i & 127;
    const double n = (double)PP;
    const double mu = gs[L * 256 + c] / n;
    const double var = gs[L * 256 + 128 + c] / n - mu * mu;
    const float rstd = (float)(1.0 / sqrt(var + 1e-5));
    const float sc = rstd * gam[L * 128 + c];
    sc_s[L][c] = sc;
    sh_s[L][c] = bet[L * 128 + c] - (float)mu * sc;
  }
  __syncthreads();

  double lS0 = 0, lS1 = 0, lQ0 = 0, lQ1 = 0;

  for (int p0 = blockIdx.x * 256; p0 < PP; p0 += gridDim.x * 256) {
    const int p = p0 + t;
    const bool act = p < PP;

    float a[128];
    {
      float u[7];
#pragma unroll
      for (int c = 0; c < 7; ++c) u[c] = act ? up[c * PP + p] : 0.f;
#pragma unroll 1
      for (int och = 0; och < 16; ++och) {
#pragma unroll
        for (int j = 0; j < 8; ++j) {
          float acc = 0.f;
#pragma unroll
          for (int c = 0; c < 7; ++c)
            acc = fmaf(w0[(och * 8 + j) * 7 + c], u[c], acc);
          a[och * 8 + j] = acc;
        }
      }
    }

#pragma unroll 1
    for (int L = 0; L < jl; ++L) {
#pragma unroll
      for (int c = 0; c < 128; ++c)
        a[c] = act ? __sinf(fmaf(a[c], sc_s[L][c], sh_s[L][c])) : 0.f;
      float b[128];
      const float* W = wc + (size_t)L * 128 * 128;
#pragma unroll 1
      for (int och = 0; och < 16; ++och) {
#pragma unroll
        for (int j = 0; j < 8; ++j) {
          float acc = 0.f;
#pragma unroll
          for (int c = 0; c < 128; ++c)
            acc = fmaf(W[(och * 8 + j) * 128 + c], a[c], acc);
          b[och * 8 + j] = acc;
        }
      }
#pragma unroll
      for (int c = 0; c < 128; ++c) a[c] = b[c];
    }

    if (mode == 0) {
#pragma unroll
      for (int o = 0; o < 128; ++o) {
        float s = a[o];
        float qv = a[o] * a[o];
#pragma unroll
        for (int d = 32; d > 0; d >>= 1) {
          s += __shfl_xor(s, d, 64);
          qv += __shfl_xor(qv, d, 64);
        }
        if ((o & 63) == lane) {
          if (o < 64) { lS0 += (double)s; lQ0 += (double)qv; }
          else        { lS1 += (double)s; lQ1 += (double)qv; }
        }
      }
    } else if (act) {
      float acc = fb[0];
#pragma unroll
      for (int c = 0; c < 128; ++c) {
        const float h = fmaf(a[c], sc_s[7][c], sh_s[7][c]);
        acc = fmaf(fw[c], __sinf(h), acc);
      }
      logits[p] = acc;
    }
  }

  if (mode == 0) {
    const int w = t >> 6;
    bred[w][lane]       = lS0;
    bred[w][64 + lane]  = lS1;
    bred[w][128 + lane] = lQ0;
    bred[w][192 + lane] = lQ1;
    __syncthreads();
    double v = bred[0][t] + bred[1][t] + bred[2][t] + bred[3][t];
    atomicAdd(&gso[t], v);
  }
}

// ---------------------------------------------------------------------------
extern "C" void kernel_launch(void* const* d_in, const int* in_sizes, int n_in,
                              void* d_out, int out_size, void* d_ws, size_t ws_size,
                              hipStream_t stream) {
  const float* xf  = (const float*)d_in[0];  // (1, N, 128)
  const float* up  = (const float*)d_in[1];  // (1, 7, M, K)  == [7][PP]
  const int*   idx = (const int*)d_in[2];    // (1, M, K)
  const float* w0  = (const float*)d_in[3];  // (128, 7)
  const float* wc  = (const float*)d_in[4];  // (7, 128, 128)
  const float* gam = (const float*)d_in[5];  // (8, 128)
  const float* bet = (const float*)d_in[6];  // (8, 128)
  const float* fw  = (const float*)d_in[7];  // (1, 128)
  const float* fb  = (const float*)d_in[8];  // (1,)
  float* out = (float*)d_out;

  char* ws = (char*)d_ws;
  const size_t zb     = (size_t)NT64 * 64 * 128 * sizeof(h16); // padded z
  const size_t statsb = 8 * 256 * sizeof(double);
  const size_t logb   = (size_t)PP * sizeof(float);
  const int NB = 1024;
  const int nbo = (MM + 3) / 4;

  if (ws_size >= zb + statsb + logb) {
    // Fast path: point-major fp16 z + block-cooperative MFMA layers.
    h16* z = (h16*)ws;
    double* gs = (double*)(ws + zb);
    float* logits = (float*)(ws + zb + statsb);

    k_zero<<<1, 256, 0, stream>>>(gs);
    k_layer0<<<dim3(NB, 4), 256, 0, stream>>>(up, w0, z, gs);
    for (int i = 1; i <= 7; ++i) {
      k_layer<<<NB, 256, 0, stream>>>(z,
                                      gs + (size_t)(i - 1) * 256,
                                      gs + (size_t)i * 256,
                                      wc + (size_t)(i - 1) * 128 * 128,
                                      gam + (size_t)(i - 1) * 128,
                                      bet + (size_t)(i - 1) * 128);
    }
    k_logits<<<2048, 256, 0, stream>>>(z, gs + 7 * 256, gam + 7 * 128,
                                       bet + 7 * 128, fw, fb, logits);
    k_out<<<nbo, 256, 0, stream>>>(logits, idx, xf, out);
  } else {
    // Fallback: recompute chain, needs only ~2.9 MiB of workspace.
    double* gs = (double*)ws;
    float* logits = (float*)(ws + statsb);

    k_zero<<<1, 256, 0, stream>>>(gs);
    for (int j = 0; j <= 7; ++j) {
      k_chain<<<NB, 256, 0, stream>>>(up, w0, wc, gam, bet, gs,
                                      gs + (size_t)j * 256, j, 0,
                                      fw, fb, logits);
    }
    k_chain<<<NB, 256, 0, stream>>>(up, w0, wc, gam, bet, gs,
                                    nullptr, 7, 1, fw, fb, logits);
    k_out<<<nbo, 256, 0, stream>>>(logits, idx, xf, out);
  }
}

// Round 7
// 1028.914 us; speedup vs baseline: 1.1114x; 1.1114x over previous
//
#include <hip/hip_runtime.h>

// Problem constants (from reference)
#define PP 712740      // M*K points
#define MM 35637       // M
#define KK 20          // K neighbors
#define NF 15872       // N points in x_feat
#define NT64 11137     // ceil(PP/64) point-tiles of 64
#define NTILES 44547   // ceil(PP/16) (k_logits / k_layer0 tiling)
// FEAT = 128 channels, W0 = 1.0, EPS = 1e-5

typedef _Float16 h16;
typedef __attribute__((ext_vector_type(8))) _Float16 f16x8;
typedef __attribute__((ext_vector_type(4))) _Float16 f16x4;
typedef __attribute__((ext_vector_type(4))) float f32x4;

// Raw workgroup barrier: waits LDS ops only (lgkmcnt), leaves global-load
// prefetches (vmcnt) in flight across the barrier. __syncthreads() would
// drain vmcnt(0) and serialize every tile on HBM latency (round-6 lesson).
#define LDS_BARRIER() asm volatile("s_waitcnt lgkmcnt(0)\n\ts_barrier" ::: "memory")

// ---------------------------------------------------------------------------
// Zero the stats accumulators (8 layers x 256 doubles).
// ---------------------------------------------------------------------------
__global__ __launch_bounds__(256) void k_zero(double* __restrict__ gs) {
  const int t = threadIdx.x;
#pragma unroll
  for (int i = 0; i < 8; ++i) gs[i * 256 + t] = 0.0;
}

// ---------------------------------------------------------------------------
// Layer 0 (K=7, VALU), strip version: blockIdx.y = ks owns channels
// [ks*32, ks*32+32). Lane (q,ln): point p=tile*16+ln, channels ks*32+q*8+j.
// ---------------------------------------------------------------------------
__global__ __launch_bounds__(256, 4) void k_layer0(
    const float* __restrict__ up,    // [7][PP]
    const float* __restrict__ w0,    // [128][7]
    h16* __restrict__ z,             // [NT64*64][128] (padded)
    double* __restrict__ gs)         // [256]: sum[128], sumsq[128]
{
  __shared__ double red[4][64];
  const int t = threadIdx.x;
  const int w = t >> 6;
  const int lane = t & 63;
  const int ln = lane & 15;
  const int q = lane >> 4;
  const int ks = blockIdx.y;         // channel strip

  float wr[8][7];
#pragma unroll
  for (int j = 0; j < 8; ++j) {
    const int c = ks * 32 + q * 8 + j;
#pragma unroll
    for (int c7 = 0; c7 < 7; ++c7) wr[j][c7] = w0[c * 7 + c7];
  }

  float sp[8], qp[8];
#pragma unroll
  for (int j = 0; j < 8; ++j) { sp[j] = 0.f; qp[j] = 0.f; }

  for (int tile = blockIdx.x * 4 + w; tile < NTILES; tile += gridDim.x * 4) {
    const int p = tile * 16 + ln;
    const bool act = p < PP;
    float u[7];
#pragma unroll
    for (int c7 = 0; c7 < 7; ++c7) u[c7] = act ? up[c7 * PP + p] : 0.f;

    f16x8 o;
#pragma unroll
    for (int j = 0; j < 8; ++j) {
      float acc = 0.f;
#pragma unroll
      for (int c7 = 0; c7 < 7; ++c7) acc = fmaf(wr[j][c7], u[c7], acc);
      o[j] = (h16)acc;
      sp[j] += acc;
      qp[j] = fmaf(acc, acc, qp[j]);
    }
    if (act) *(f16x8*)(z + (size_t)p * 128 + ks * 32 + q * 8) = o;
  }

#pragma unroll
  for (int j = 0; j < 8; ++j) {
#pragma unroll
    for (int d = 1; d < 16; d <<= 1) {
      sp[j] += __shfl_xor(sp[j], d, 64);
      qp[j] += __shfl_xor(qp[j], d, 64);
    }
  }
  if (ln == 0) {
#pragma unroll
    for (int j = 0; j < 8; ++j) {
      red[w][q * 8 + j] = (double)sp[j];
      red[w][32 + q * 8 + j] = (double)qp[j];
    }
  }
  __syncthreads();
  if (t < 64) {
    const double v = red[0][t] + red[1][t] + red[2][t] + red[3][t];
    const int c = ks * 32 + (t & 31);
    atomicAdd(&gs[(t >> 5) * 128 + c], v);
  }
}

// ---------------------------------------------------------------------------
// Middle layer (x7), block-cooperative MFMA, prefetch alive across barriers:
//  - Block tile = 64 points, double-buffered LDS frag staging.
//  - Per iteration: [prefetch tile+G] [BN+sine stage] [LDS_BARRIER]
//    [MFMA + stores]. Prefetch latency covered by a full tile of work.
//  - Wave w computes output channels [w*32, w*32+32): W-frags 32 VGPR.
//    Swapped MFMA operands -> D[o][p] -> direct 8B stores, no transpose.
// ---------------------------------------------------------------------------
__global__ __launch_bounds__(256, 3) void k_layer(
    h16* __restrict__ z,              // [NT64*64][128], in-place
    const double* __restrict__ gsp,   // stats of previous layer output
    double* __restrict__ gso,         // stats of this layer output
    const float* __restrict__ W,      // [128][128] fp32
    const float* __restrict__ gamma,  // [128]
    const float* __restrict__ beta)   // [128]
{
  __shared__ h16 stage[2][16 * 64 * 8];  // [buf][(st*4+ks)*64 + lane][8]
  const int t = threadIdx.x;
  const int w = t >> 6;
  const int lane = t & 63;
  const int ln = lane & 15;
  const int q = lane >> 4;

  // BN constants for this thread's 8 fixed channels: c = w*32 + q*8 + j
  float sc[8], sh[8];
#pragma unroll
  for (int j = 0; j < 8; ++j) {
    const int c = w * 32 + q * 8 + j;
    const double n = (double)PP;
    const double mu = gsp[c] / n;
    const double var = gsp[128 + c] / n - mu * mu;
    const float rstd = (float)(1.0 / sqrt(var + 1e-5));
    sc[j] = rstd * gamma[c];
    sh[j] = beta[c] - (float)mu * sc[j];
  }

  // Persistent W fragments (A-operand): rows o = w*32 + nt*16 + ln
  f16x8 bfr[2][4];
#pragma unroll
  for (int nt = 0; nt < 2; ++nt) {
    const float* wrow = W + (size_t)(w * 32 + nt * 16 + ln) * 128;
#pragma unroll
    for (int ks = 0; ks < 4; ++ks) {
      const float* src = wrow + ks * 32 + q * 8;
      const float4 aa = *(const float4*)src;
      const float4 bb = *(const float4*)(src + 4);
      f16x8 b;
      b[0] = (h16)aa.x; b[1] = (h16)aa.y; b[2] = (h16)aa.z; b[3] = (h16)aa.w;
      b[4] = (h16)bb.x; b[5] = (h16)bb.y; b[6] = (h16)bb.z; b[7] = (h16)bb.w;
      bfr[nt][ks] = b;
    }
  }

  float sp[8], qp[8];
#pragma unroll
  for (int i = 0; i < 8; ++i) { sp[i] = 0.f; qp[i] = 0.f; }

  const int G = gridDim.x;
  int tile = blockIdx.x;
  int buf = 0;

  // initial prefetch: wave loads 64 points x its 32-channel slice
  f16x8 raw[4];
#pragma unroll
  for (int st = 0; st < 4; ++st)
    raw[st] = *(const f16x8*)(z + (size_t)(tile * 64 + st * 16 + ln) * 128 +
                              w * 32 + q * 8);

  while (tile < NT64) {
    // ---- prefetch next tile FIRST (latency covered by this whole iter) ----
    const int nxt = tile + G;
    const int npf = (nxt < NT64) ? nxt : tile;   // clamp: safe re-read
    f16x8 rawn[4];
#pragma unroll
    for (int st = 0; st < 4; ++st)
      rawn[st] = *(const f16x8*)(z + (size_t)(npf * 64 + st * 16 + ln) * 128 +
                                 w * 32 + q * 8);

    // ---- stage: BN + sine -> LDS frag-slots (slot id = st*4 + w) ----
#pragma unroll
    for (int st = 0; st < 4; ++st) {
      const int p = tile * 64 + st * 16 + ln;
      const bool act = p < PP;
      f16x8 a;
#pragma unroll
      for (int j = 0; j < 8; ++j) {
        const float h = fmaf((float)raw[st][j], sc[j], sh[j]);
        a[j] = act ? (h16)__sinf(h) : (h16)0.f;
      }
      *(f16x8*)&stage[buf][((st * 4 + w) * 64 + lane) * 8] = a;
    }

    LDS_BARRIER();   // LDS visibility only; rawn stays in flight

    // ---- MFMA phase: D[o][p] = sum_c W[o][c] * act[p][c] ----
#pragma unroll
    for (int st = 0; st < 4; ++st) {
      f16x8 bf[4];
#pragma unroll
      for (int ks = 0; ks < 4; ++ks)
        bf[ks] = *(const f16x8*)&stage[buf][((st * 4 + ks) * 64 + lane) * 8];

      f32x4 acc0 = (f32x4){0.f, 0.f, 0.f, 0.f};
      f32x4 acc1 = (f32x4){0.f, 0.f, 0.f, 0.f};
#pragma unroll
      for (int ks = 0; ks < 4; ++ks) {
        acc0 = __builtin_amdgcn_mfma_f32_16x16x32_f16(bfr[0][ks], bf[ks], acc0, 0, 0, 0);
        acc1 = __builtin_amdgcn_mfma_f32_16x16x32_f16(bfr[1][ks], bf[ks], acc1, 0, 0, 0);
      }

      const int p = tile * 64 + st * 16 + ln;
      const bool act = p < PP;
      {
        f16x4 v;
#pragma unroll
        for (int r = 0; r < 4; ++r) {
          const float d = acc0[r];
          sp[r] += d; qp[r] = fmaf(d, d, qp[r]);
          v[r] = (h16)d;
        }
        if (act) *(f16x4*)(z + (size_t)p * 128 + w * 32 + q * 4) = v;
      }
      {
        f16x4 v;
#pragma unroll
        for (int r = 0; r < 4; ++r) {
          const float d = acc1[r];
          sp[4 + r] += d; qp[4 + r] = fmaf(d, d, qp[4 + r]);
          v[r] = (h16)d;
        }
        if (act) *(f16x4*)(z + (size_t)p * 128 + w * 32 + 16 + q * 4) = v;
      }
    }

    tile = nxt;
    buf ^= 1;
#pragma unroll
    for (int st = 0; st < 4; ++st) raw[st] = rawn[st];
  }

  // ---- stats: reduce over the 16 ln-lanes, then f64 atomics ----
#pragma unroll
  for (int s = 0; s < 8; ++s) {
#pragma unroll
    for (int d = 1; d < 16; d <<= 1) {
      sp[s] += __shfl_xor(sp[s], d, 64);
      qp[s] += __shfl_xor(qp[s], d, 64);
    }
  }
  if (ln == 0) {
#pragma unroll
    for (int nt = 0; nt < 2; ++nt)
#pragma unroll
      for (int r = 0; r < 4; ++r) {
        const int c = w * 32 + nt * 16 + q * 4 + r;
        atomicAdd(&gso[c], (double)sp[nt * 4 + r]);
        atomicAdd(&gso[128 + c], (double)qp[nt * 4 + r]);
      }
  }
}

// ---------------------------------------------------------------------------
// Final conv (128->1) with BN7+sine, z point-major.
// ---------------------------------------------------------------------------
__global__ __launch_bounds__(256) void k_logits(
    const h16* __restrict__ z,
    const double* __restrict__ gsp,
    const float* __restrict__ gamma,
    const float* __restrict__ beta,
    const float* __restrict__ fw,
    const float* __restrict__ fb,
    float* __restrict__ logits)
{
  __shared__ float sc_s[128], sh_s[128], fws[128];
  const int t = threadIdx.x;
  if (t < 128) {
    const double n = (double)PP;
    const double mu = gsp[t] / n;
    const double var = gsp[128 + t] / n - mu * mu;
    const float rstd = (float)(1.0 / sqrt(var + 1e-5));
    const float sc = rstd * gamma[t];
    sc_s[t] = sc;
    sh_s[t] = beta[t] - (float)mu * sc;
    fws[t] = fw[t];
  }
  __syncthreads();

  const int w = t >> 6;
  const int lane = t & 63;
  const int ln = lane & 15;
  const int q = lane >> 4;
  const float fbv = fb[0];

  const int gw = blockIdx.x * 4 + w;
  for (int tile = gw; tile < NTILES; tile += gridDim.x * 4) {
    const int p = tile * 16 + ln;
    float part = 0.f;
    if (p < PP) {
#pragma unroll
      for (int ks = 0; ks < 4; ++ks) {
        const f16x8 raw = *(const f16x8*)(z + (size_t)p * 128 + ks * 32 + q * 8);
#pragma unroll
        for (int j = 0; j < 8; ++j) {
          const int c = ks * 32 + q * 8 + j;
          part = fmaf(fws[c], __sinf(fmaf((float)raw[j], sc_s[c], sh_s[c])), part);
        }
      }
    }
    part += __shfl_xor(part, 16, 64);
    part += __shfl_xor(part, 32, 64);
    if (q == 0 && p < PP) logits[p] = part + fbv;
  }
}

// ---------------------------------------------------------------------------
// Softmax over K=20 per m + gather-weighted sum of x_feat rows. 1 wave per m.
// ---------------------------------------------------------------------------
__global__ __launch_bounds__(256) void k_out(
    const float* __restrict__ logits,  // [PP]
    const int* __restrict__ idx,       // [MM][KK]
    const float* __restrict__ xf,      // [NF][128]
    float* __restrict__ out)           // [MM][128]
{
  const int gw = (int)((blockIdx.x * 256 + threadIdx.x) >> 6);
  const int lane = threadIdx.x & 63;
  if (gw >= MM) return;
  const int m = gw;

  float l[KK];
#pragma unroll
  for (int k = 0; k < KK; ++k) l[k] = logits[m * KK + k];
  float mx = l[0];
#pragma unroll
  for (int k = 1; k < KK; ++k) mx = fmaxf(mx, l[k]);
  float ssum = 0.f;
#pragma unroll
  for (int k = 0; k < KK; ++k) { l[k] = __expf(l[k] - mx); ssum += l[k]; }
  const float inv = 1.f / ssum;

  float a0 = 0.f, a1 = 0.f;
#pragma unroll
  for (int k = 0; k < KK; ++k) {
    const int r = idx[m * KK + k];
    const float wk = l[k] * inv;
    a0 = fmaf(wk, xf[r * 128 + lane], a0);
    a1 = fmaf(wk, xf[r * 128 + 64 + lane], a1);
  }
  out[m * 128 + lane] = a0;
  out[m * 128 + 64 + lane] = a1;
}

// ---------------------------------------------------------------------------
// Fallback (small workspace): recompute chain in registers per point.
// ---------------------------------------------------------------------------
__global__ __launch_bounds__(256) void k_chain(
    const float* __restrict__ up,
    const float* __restrict__ w0,
    const float* __restrict__ wc,
    const float* __restrict__ gam,
    const float* __restrict__ bet,
    const double* __restrict__ gs,
    double* __restrict__ gso,
    int jl, int mode,
    const float* __restrict__ fw,
    const float* __restrict__ fb,
    float* __restrict__ logits)
{
  __shared__ float sc_s[8][128], sh_s[8][128];
  __shared__ double bred[4][256];
  const int t = threadIdx.x;
  const int lane = t & 63;

  const int nbn = (mode == 0) ? jl : 8;
  for (int i = t; i < nbn * 128; i += 256) {
    const int L = i >> 7, c = i & 127;
    const double n = (double)PP;
    const double mu = gs[L * 256 + c] / n;
    const double var = gs[L * 256 + 128 + c] / n - mu * mu;
    const float rstd = (float)(1.0 / sqrt(var + 1e-5));
    const float sc = rstd * gam[L * 128 + c];
    sc_s[L][c] = sc;
    sh_s[L][c] = bet[L * 128 + c] - (float)mu * sc;
  }
  __syncthreads();

  double lS0 = 0, lS1 = 0, lQ0 = 0, lQ1 = 0;

  for (int p0 = blockIdx.x * 256; p0 < PP; p0 += gridDim.x * 256) {
    const int p = p0 + t;
    const bool act = p < PP;

    float a[128];
    {
      float u[7];
#pragma unroll
      for (int c = 0; c < 7; ++c) u[c] = act ? up[c * PP + p] : 0.f;
#pragma unroll 1
      for (int och = 0; och < 16; ++och) {
#pragma unroll
        for (int j = 0; j < 8; ++j) {
          float acc = 0.f;
#pragma unroll
          for (int c = 0; c < 7; ++c)
            acc = fmaf(w0[(och * 8 + j) * 7 + c], u[c], acc);
          a[och * 8 + j] = acc;
        }
      }
    }

#pragma unroll 1
    for (int L = 0; L < jl; ++L) {
#pragma unroll
      for (int c = 0; c < 128; ++c)
        a[c] = act ? __sinf(fmaf(a[c], sc_s[L][c], sh_s[L][c])) : 0.f;
      float b[128];
      const float* W = wc + (size_t)L * 128 * 128;
#pragma unroll 1
      for (int och = 0; och < 16; ++och) {
#pragma unroll
        for (int j = 0; j < 8; ++j) {
          float acc = 0.f;
#pragma unroll
          for (int c = 0; c < 128; ++c)
            acc = fmaf(W[(och * 8 + j) * 128 + c], a[c], acc);
          b[och * 8 + j] = acc;
        }
      }
#pragma unroll
      for (int c = 0; c < 128; ++c) a[c] = b[c];
    }

    if (mode == 0) {
#pragma unroll
      for (int o = 0; o < 128; ++o) {
        float s = a[o];
        float qv = a[o] * a[o];
#pragma unroll
        for (int d = 32; d > 0; d >>= 1) {
          s += __shfl_xor(s, d, 64);
          qv += __shfl_xor(qv, d, 64);
        }
        if ((o & 63) == lane) {
          if (o < 64) { lS0 += (double)s; lQ0 += (double)qv; }
          else        { lS1 += (double)s; lQ1 += (double)qv; }
        }
      }
    } else if (act) {
      float acc = fb[0];
#pragma unroll
      for (int c = 0; c < 128; ++c) {
        const float h = fmaf(a[c], sc_s[7][c], sh_s[7][c]);
        acc = fmaf(fw[c], __sinf(h), acc);
      }
      logits[p] = acc;
    }
  }

  if (mode == 0) {
    const int w = t >> 6;
    bred[w][lane]       = lS0;
    bred[w][64 + lane]  = lS1;
    bred[w][128 + lane] = lQ0;
    bred[w][192 + lane] = lQ1;
    __syncthreads();
    double v = bred[0][t] + bred[1][t] + bred[2][t] + bred[3][t];
    atomicAdd(&gso[t], v);
  }
}

// ---------------------------------------------------------------------------
extern "C" void kernel_launch(void* const* d_in, const int* in_sizes, int n_in,
                              void* d_out, int out_size, void* d_ws, size_t ws_size,
                              hipStream_t stream) {
  const float* xf  = (const float*)d_in[0];  // (1, N, 128)
  const float* up  = (const float*)d_in[1];  // (1, 7, M, K)  == [7][PP]
  const int*   idx = (const int*)d_in[2];    // (1, M, K)
  const float* w0  = (const float*)d_in[3];  // (128, 7)
  const float* wc  = (const float*)d_in[4];  // (7, 128, 128)
  const float* gam = (const float*)d_in[5];  // (8, 128)
  const float* bet = (const float*)d_in[6];  // (8, 128)
  const float* fw  = (const float*)d_in[7];  // (1, 128)
  const float* fb  = (const float*)d_in[8];  // (1,)
  float* out = (float*)d_out;

  char* ws = (char*)d_ws;
  const size_t zb     = (size_t)NT64 * 64 * 128 * sizeof(h16); // padded z
  const size_t statsb = 8 * 256 * sizeof(double);
  const size_t logb   = (size_t)PP * sizeof(float);
  const int NB = 1024;
  const int NBL = 768;   // k_layer: 3 blocks/CU x 256 CUs resident exactly
  const int nbo = (MM + 3) / 4;

  if (ws_size >= zb + statsb + logb) {
    // Fast path: point-major fp16 z + block-cooperative MFMA layers.
    h16* z = (h16*)ws;
    double* gs = (double*)(ws + zb);
    float* logits = (float*)(ws + zb + statsb);

    k_zero<<<1, 256, 0, stream>>>(gs);
    k_layer0<<<dim3(NB, 4), 256, 0, stream>>>(up, w0, z, gs);
    for (int i = 1; i <= 7; ++i) {
      k_layer<<<NBL, 256, 0, stream>>>(z,
                                       gs + (size_t)(i - 1) * 256,
                                       gs + (size_t)i * 256,
                                       wc + (size_t)(i - 1) * 128 * 128,
                                       gam + (size_t)(i - 1) * 128,
                                       bet + (size_t)(i - 1) * 128);
    }
    k_logits<<<2048, 256, 0, stream>>>(z, gs + 7 * 256, gam + 7 * 128,
                                       bet + 7 * 128, fw, fb, logits);
    k_out<<<nbo, 256, 0, stream>>>(logits, idx, xf, out);
  } else {
    // Fallback: recompute chain, needs only ~2.9 MiB of workspace.
    double* gs = (double*)ws;
    float* logits = (float*)(ws + statsb);

    k_zero<<<1, 256, 0, stream>>>(gs);
    for (int j = 0; j <= 7; ++j) {
      k_chain<<<NB, 256, 0, stream>>>(up, w0, wc, gam, bet, gs,
                                      gs + (size_t)j * 256, j, 0,
                                      fw, fb, logits);
    }
    k_chain<<<NB, 256, 0, stream>>>(up, w0, wc, gam, bet, gs,
                                    nullptr, 7, 1, fw, fb, logits);
    k_out<<<nbo, 256, 0, stream>>>(logits, idx, xf, out);
  }
}

// Round 8
// 970.230 us; speedup vs baseline: 1.1786x; 1.0605x over previous
//
#include <hip/hip_runtime.h>

// Problem constants (from reference)
#define PP 712740      // M*K points
#define MM 35637       // M
#define KK 20          // K neighbors
#define NF 15872       // N points in x_feat
#define NT64 11137     // ceil(PP/64) point-tiles of 64
#define NTILES 44547   // ceil(PP/16) (k_logits / k_layer0 tiling)
// FEAT = 128 channels, W0 = 1.0, EPS = 1e-5

typedef _Float16 h16;
typedef __attribute__((ext_vector_type(8))) _Float16 f16x8;
typedef __attribute__((ext_vector_type(4))) _Float16 f16x4;
typedef __attribute__((ext_vector_type(4))) float f32x4;

// z fragment-slot layout: element (p,c) lives at
//   tile64*8192 + ((st*4 + ks)*64 + q*16 + ln)*8 + j
// with tile64=p>>6, st=(p>>4)&3, ln=p&15, ks=c>>5, q=(c>>3)&3, j=c&7.
// Every global access (frag loads, D-quad stores, layer0 stores, logits
// loads) is >=512B contiguous per wave instruction in this layout.
#define ZIDX(tile64, grp, lidx) ((size_t)(tile64) * 8192 + ((grp) * 64 + (lidx)) * 8)

// Raw workgroup barrier: waits LDS ops only, leaves global-load prefetches
// (vmcnt) in flight across the barrier (round-6/7 lesson).
#define LDS_BARRIER() asm volatile("s_waitcnt lgkmcnt(0)\n\ts_barrier" ::: "memory")

// ---------------------------------------------------------------------------
// Zero the stats accumulators (8 layers x 256 doubles).
// ---------------------------------------------------------------------------
__global__ __launch_bounds__(256) void k_zero(double* __restrict__ gs) {
  const int t = threadIdx.x;
#pragma unroll
  for (int i = 0; i < 8; ++i) gs[i * 256 + t] = 0.0;
}

// ---------------------------------------------------------------------------
// Layer 0 (K=7, VALU), strip version: blockIdx.y = ks owns channels
// [ks*32, ks*32+32). Stores to fragment-slot layout: per instruction the
// 64 lanes (q,ln) cover (q*16+ln)*16B = 1KB fully contiguous.
// ---------------------------------------------------------------------------
__global__ __launch_bounds__(256, 4) void k_layer0(
    const float* __restrict__ up,    // [7][PP]
    const float* __restrict__ w0,    // [128][7]
    h16* __restrict__ z,             // frag-slot layout, NT64*8192 elems
    double* __restrict__ gs)         // [256]: sum[128], sumsq[128]
{
  __shared__ double red[4][64];
  const int t = threadIdx.x;
  const int w = t >> 6;
  const int lane = t & 63;
  const int ln = lane & 15;
  const int q = lane >> 4;
  const int ks = blockIdx.y;         // channel strip

  float wr[8][7];
#pragma unroll
  for (int j = 0; j < 8; ++j) {
    const int c = ks * 32 + q * 8 + j;
#pragma unroll
    for (int c7 = 0; c7 < 7; ++c7) wr[j][c7] = w0[c * 7 + c7];
  }

  float sp[8], qp[8];
#pragma unroll
  for (int j = 0; j < 8; ++j) { sp[j] = 0.f; qp[j] = 0.f; }

  for (int pt = blockIdx.x * 4 + w; pt < NTILES; pt += gridDim.x * 4) {
    const int p = pt * 16 + ln;
    const bool act = p < PP;
    float u[7];
#pragma unroll
    for (int c7 = 0; c7 < 7; ++c7) u[c7] = act ? up[c7 * PP + p] : 0.f;

    f16x8 o;
#pragma unroll
    for (int j = 0; j < 8; ++j) {
      float acc = 0.f;
#pragma unroll
      for (int c7 = 0; c7 < 7; ++c7) acc = fmaf(wr[j][c7], u[c7], acc);
      o[j] = (h16)acc;
      sp[j] += acc;
      qp[j] = fmaf(acc, acc, qp[j]);
    }
    if (act)
      *(f16x8*)(z + ZIDX(pt >> 2, (pt & 3) * 4 + ks, q * 16 + ln)) = o;
  }

#pragma unroll
  for (int j = 0; j < 8; ++j) {
#pragma unroll
    for (int d = 1; d < 16; d <<= 1) {
      sp[j] += __shfl_xor(sp[j], d, 64);
      qp[j] += __shfl_xor(qp[j], d, 64);
    }
  }
  if (ln == 0) {
#pragma unroll
    for (int j = 0; j < 8; ++j) {
      red[w][q * 8 + j] = (double)sp[j];
      red[w][32 + q * 8 + j] = (double)qp[j];
    }
  }
  __syncthreads();
  if (t < 64) {
    const double v = red[0][t] + red[1][t] + red[2][t] + red[3][t];
    const int c = ks * 32 + (t & 31);
    atomicAdd(&gs[(t >> 5) * 128 + c], v);
  }
}

// ---------------------------------------------------------------------------
// Middle layer (x7), block-cooperative MFMA on frag-slot z:
//  - Wave w loads its 4 stage groups (st, ks=w) as 1KB contiguous bursts,
//    applies BN+sine (8 fixed channels/thread), writes LDS frag-slots.
//  - After LDS_BARRIER, wave w (output chans w*32..+31) reads all 16 frags
//    (lane-contiguous ds_read_b128), 32 MFMAs, stores D quads directly to
//    global: each store instruction covers 512B contiguous.
//  - Double-buffered LDS, 1-deep cross-tile prefetch, one barrier per tile.
// ---------------------------------------------------------------------------
__global__ __launch_bounds__(256, 3) void k_layer(
    h16* __restrict__ z,              // frag-slot layout, in-place
    const double* __restrict__ gsp,   // stats of previous layer output
    double* __restrict__ gso,         // stats of this layer output
    const float* __restrict__ W,      // [128][128] fp32
    const float* __restrict__ gamma,  // [128]
    const float* __restrict__ beta)   // [128]
{
  __shared__ h16 stage[2][8192];      // [buf][(st*4+ks)*64 + lane][8]
  const int t = threadIdx.x;
  const int w = t >> 6;
  const int lane = t & 63;
  const int ln = lane & 15;
  const int q = lane >> 4;

  // BN constants for this thread's 8 staged channels: c = w*32 + q*8 + j
  float sc[8], sh[8];
#pragma unroll
  for (int j = 0; j < 8; ++j) {
    const int c = w * 32 + q * 8 + j;
    const double n = (double)PP;
    const double mu = gsp[c] / n;
    const double var = gsp[128 + c] / n - mu * mu;
    const float rstd = (float)(1.0 / sqrt(var + 1e-5));
    sc[j] = rstd * gamma[c];
    sh[j] = beta[c] - (float)mu * sc[j];
  }

  // Persistent W fragments (A-operand): rows o = w*32 + nt*16 + ln
  f16x8 bfr[2][4];
#pragma unroll
  for (int nt = 0; nt < 2; ++nt) {
    const float* wrow = W + (size_t)(w * 32 + nt * 16 + ln) * 128;
#pragma unroll
    for (int ks = 0; ks < 4; ++ks) {
      const float* src = wrow + ks * 32 + q * 8;
      const float4 aa = *(const float4*)src;
      const float4 bb = *(const float4*)(src + 4);
      f16x8 b;
      b[0] = (h16)aa.x; b[1] = (h16)aa.y; b[2] = (h16)aa.z; b[3] = (h16)aa.w;
      b[4] = (h16)bb.x; b[5] = (h16)bb.y; b[6] = (h16)bb.z; b[7] = (h16)bb.w;
      bfr[nt][ks] = b;
    }
  }

  float sp[8], qp[8];
#pragma unroll
  for (int i = 0; i < 8; ++i) { sp[i] = 0.f; qp[i] = 0.f; }

  const int G = gridDim.x;
  int tile = blockIdx.x;
  int buf = 0;

  // initial prefetch: wave's 4 stage groups (st, ks=w), 1KB bursts
  f16x8 raw[4];
#pragma unroll
  for (int st = 0; st < 4; ++st)
    raw[st] = *(const f16x8*)(z + ZIDX(tile, st * 4 + w, lane));

  while (tile < NT64) {
    // ---- prefetch next tile (stays in flight across the barrier) ----
    const int nxt = tile + G;
    const int npf = (nxt < NT64) ? nxt : tile;   // clamp: safe re-read
    f16x8 rawn[4];
#pragma unroll
    for (int st = 0; st < 4; ++st)
      rawn[st] = *(const f16x8*)(z + ZIDX(npf, st * 4 + w, lane));

    // ---- stage: BN + sine -> LDS frag-slots (identity copy layout) ----
#pragma unroll
    for (int st = 0; st < 4; ++st) {
      const int p = tile * 64 + st * 16 + ln;
      const bool act = p < PP;
      f16x8 a;
#pragma unroll
      for (int j = 0; j < 8; ++j) {
        const float h = fmaf((float)raw[st][j], sc[j], sh[j]);
        a[j] = act ? (h16)__sinf(h) : (h16)0.f;
      }
      *(f16x8*)&stage[buf][((st * 4 + w) * 64 + lane) * 8] = a;
    }

    LDS_BARRIER();

    // ---- MFMA: D[o][p] = sum_c W[o][c]*act[p][c]; direct 512B stores ----
#pragma unroll
    for (int st = 0; st < 4; ++st) {
      f16x8 bf[4];
#pragma unroll
      for (int ks = 0; ks < 4; ++ks)
        bf[ks] = *(const f16x8*)&stage[buf][((st * 4 + ks) * 64 + lane) * 8];

      f32x4 acc0 = (f32x4){0.f, 0.f, 0.f, 0.f};
      f32x4 acc1 = (f32x4){0.f, 0.f, 0.f, 0.f};
#pragma unroll
      for (int ks = 0; ks < 4; ++ks) {
        acc0 = __builtin_amdgcn_mfma_f32_16x16x32_f16(bfr[0][ks], bf[ks], acc0, 0, 0, 0);
        acc1 = __builtin_amdgcn_mfma_f32_16x16x32_f16(bfr[1][ks], bf[ks], acc1, 0, 0, 0);
      }

      const int p = tile * 64 + st * 16 + ln;
      const bool act = p < PP;
      // D quad (o = w*32 + nt*16 + q*4 + r) -> frag slot:
      //   group (st, ks_o=w), lane-in-slot (nt*2+(q>>1))*16+ln, j=(q&1)*4+r
      {
        f16x4 v;
#pragma unroll
        for (int r = 0; r < 4; ++r) {
          const float d = acc0[r];
          sp[r] += d; qp[r] = fmaf(d, d, qp[r]);
          v[r] = (h16)d;
        }
        if (act)
          *(f16x4*)(z + ZIDX(tile, st * 4 + w, (0 + (q >> 1)) * 16 + ln) +
                    (q & 1) * 4) = v;
      }
      {
        f16x4 v;
#pragma unroll
        for (int r = 0; r < 4; ++r) {
          const float d = acc1[r];
          sp[4 + r] += d; qp[4 + r] = fmaf(d, d, qp[4 + r]);
          v[r] = (h16)d;
        }
        if (act)
          *(f16x4*)(z + ZIDX(tile, st * 4 + w, (2 + (q >> 1)) * 16 + ln) +
                    (q & 1) * 4) = v;
      }
    }

    tile = nxt;
    buf ^= 1;
#pragma unroll
    for (int st = 0; st < 4; ++st) raw[st] = rawn[st];
  }

  // ---- stats: reduce over the 16 ln-lanes, then f64 atomics ----
#pragma unroll
  for (int s = 0; s < 8; ++s) {
#pragma unroll
    for (int d = 1; d < 16; d <<= 1) {
      sp[s] += __shfl_xor(sp[s], d, 64);
      qp[s] += __shfl_xor(qp[s], d, 64);
    }
  }
  if (ln == 0) {
#pragma unroll
    for (int nt = 0; nt < 2; ++nt)
#pragma unroll
      for (int r = 0; r < 4; ++r) {
        const int c = w * 32 + nt * 16 + q * 4 + r;
        atomicAdd(&gso[c], (double)sp[nt * 4 + r]);
        atomicAdd(&gso[128 + c], (double)qp[nt * 4 + r]);
      }
  }
}

// ---------------------------------------------------------------------------
// Final conv (128->1) with BN7+sine, frag-slot z: loads are 1KB bursts.
// ---------------------------------------------------------------------------
__global__ __launch_bounds__(256) void k_logits(
    const h16* __restrict__ z,
    const double* __restrict__ gsp,
    const float* __restrict__ gamma,
    const float* __restrict__ beta,
    const float* __restrict__ fw,
    const float* __restrict__ fb,
    float* __restrict__ logits)
{
  __shared__ float sc_s[128], sh_s[128], fws[128];
  const int t = threadIdx.x;
  if (t < 128) {
    const double n = (double)PP;
    const double mu = gsp[t] / n;
    const double var = gsp[128 + t] / n - mu * mu;
    const float rstd = (float)(1.0 / sqrt(var + 1e-5));
    const float sc = rstd * gamma[t];
    sc_s[t] = sc;
    sh_s[t] = beta[t] - (float)mu * sc;
    fws[t] = fw[t];
  }
  __syncthreads();

  const int w = t >> 6;
  const int lane = t & 63;
  const int ln = lane & 15;
  const int q = lane >> 4;
  const float fbv = fb[0];

  const int gw = blockIdx.x * 4 + w;
  for (int pt = gw; pt < NTILES; pt += gridDim.x * 4) {
    const int p = pt * 16 + ln;
    float part = 0.f;
    if (p < PP) {
#pragma unroll
      for (int ks = 0; ks < 4; ++ks) {
        const f16x8 raw =
            *(const f16x8*)(z + ZIDX(pt >> 2, (pt & 3) * 4 + ks, q * 16 + ln));
#pragma unroll
        for (int j = 0; j < 8; ++j) {
          const int c = ks * 32 + q * 8 + j;
          part = fmaf(fws[c], __sinf(fmaf((float)raw[j], sc_s[c], sh_s[c])), part);
        }
      }
    }
    part += __shfl_xor(part, 16, 64);
    part += __shfl_xor(part, 32, 64);
    if (q == 0 && p < PP) logits[p] = part + fbv;
  }
}

// ---------------------------------------------------------------------------
// Softmax over K=20 per m + gather-weighted sum of x_feat rows. 1 wave per m.
// ---------------------------------------------------------------------------
__global__ __launch_bounds__(256) void k_out(
    const float* __restrict__ logits,  // [PP]
    const int* __restrict__ idx,       // [MM][KK]
    const float* __restrict__ xf,      // [NF][128]
    float* __restrict__ out)           // [MM][128]
{
  const int gw = (int)((blockIdx.x * 256 + threadIdx.x) >> 6);
  const int lane = threadIdx.x & 63;
  if (gw >= MM) return;
  const int m = gw;

  float l[KK];
#pragma unroll
  for (int k = 0; k < KK; ++k) l[k] = logits[m * KK + k];
  float mx = l[0];
#pragma unroll
  for (int k = 1; k < KK; ++k) mx = fmaxf(mx, l[k]);
  float ssum = 0.f;
#pragma unroll
  for (int k = 0; k < KK; ++k) { l[k] = __expf(l[k] - mx); ssum += l[k]; }
  const float inv = 1.f / ssum;

  float a0 = 0.f, a1 = 0.f;
#pragma unroll
  for (int k = 0; k < KK; ++k) {
    const int r = idx[m * KK + k];
    const float wk = l[k] * inv;
    a0 = fmaf(wk, xf[r * 128 + lane], a0);
    a1 = fmaf(wk, xf[r * 128 + 64 + lane], a1);
  }
  out[m * 128 + lane] = a0;
  out[m * 128 + 64 + lane] = a1;
}

// ---------------------------------------------------------------------------
// Fallback (small workspace): recompute chain in registers per point.
// ---------------------------------------------------------------------------
__global__ __launch_bounds__(256) void k_chain(
    const float* __restrict__ up,
    const float* __restrict__ w0,
    const float* __restrict__ wc,
    const float* __restrict__ gam,
    const float* __restrict__ bet,
    const double* __restrict__ gs,
    double* __restrict__ gso,
    int jl, int mode,
    const float* __restrict__ fw,
    const float* __restrict__ fb,
    float* __restrict__ logits)
{
  __shared__ float sc_s[8][128], sh_s[8][128];
  __shared__ double bred[4][256];
  const int t = threadIdx.x;
  const int lane = t & 63;

  const int nbn = (mode == 0) ? jl : 8;
  for (int i = t; i < nbn * 128; i += 256) {
    const int L = i >> 7, c = i & 127;
    const double n = (double)PP;
    const double mu = gs[L * 256 + c] / n;
    const double var = gs[L * 256 + 128 + c] / n - mu * mu;
    const float rstd = (float)(1.0 / sqrt(var + 1e-5));
    const float sc = rstd * gam[L * 128 + c];
    sc_s[L][c] = sc;
    sh_s[L][c] = bet[L * 128 + c] - (float)mu * sc;
  }
  __syncthreads();

  double lS0 = 0, lS1 = 0, lQ0 = 0, lQ1 = 0;

  for (int p0 = blockIdx.x * 256; p0 < PP; p0 += gridDim.x * 256) {
    const int p = p0 + t;
    const bool act = p < PP;

    float a[128];
    {
      float u[7];
#pragma unroll
      for (int c = 0; c < 7; ++c) u[c] = act ? up[c * PP + p] : 0.f;
#pragma unroll 1
      for (int och = 0; och < 16; ++och) {
#pragma unroll
        for (int j = 0; j < 8; ++j) {
          float acc = 0.f;
#pragma unroll
          for (int c = 0; c < 7; ++c)
            acc = fmaf(w0[(och * 8 + j) * 7 + c], u[c], acc);
          a[och * 8 + j] = acc;
        }
      }
    }

#pragma unroll 1
    for (int L = 0; L < jl; ++L) {
#pragma unroll
      for (int c = 0; c < 128; ++c)
        a[c] = act ? __sinf(fmaf(a[c], sc_s[L][c], sh_s[L][c])) : 0.f;
      float b[128];
      const float* W = wc + (size_t)L * 128 * 128;
#pragma unroll 1
      for (int och = 0; och < 16; ++och) {
#pragma unroll
        for (int j = 0; j < 8; ++j) {
          float acc = 0.f;
#pragma unroll
          for (int c = 0; c < 128; ++c)
            acc = fmaf(W[(och * 8 + j) * 128 + c], a[c], acc);
          b[och * 8 + j] = acc;
        }
      }
#pragma unroll
      for (int c = 0; c < 128; ++c) a[c] = b[c];
    }

    if (mode == 0) {
#pragma unroll
      for (int o = 0; o < 128; ++o) {
        float s = a[o];
        float qv = a[o] * a[o];
#pragma unroll
        for (int d = 32; d > 0; d >>= 1) {
          s += __shfl_xor(s, d, 64);
          qv += __shfl_xor(qv, d, 64);
        }
        if ((o & 63) == lane) {
          if (o < 64) { lS0 += (double)s; lQ0 += (double)qv; }
          else        { lS1 += (double)s; lQ1 += (double)qv; }
        }
      }
    } else if (act) {
      float acc = fb[0];
#pragma unroll
      for (int c = 0; c < 128; ++c) {
        const float h = fmaf(a[c], sc_s[7][c], sh_s[7][c]);
        acc = fmaf(fw[c], __sinf(h), acc);
      }
      logits[p] = acc;
    }
  }

  if (mode == 0) {
    const int w = t >> 6;
    bred[w][lane]       = lS0;
    bred[w][64 + lane]  = lS1;
    bred[w][128 + lane] = lQ0;
    bred[w][192 + lane] = lQ1;
    __syncthreads();
    double v = bred[0][t] + bred[1][t] + bred[2][t] + bred[3][t];
    atomicAdd(&gso[t], v);
  }
}

// ---------------------------------------------------------------------------
extern "C" void kernel_launch(void* const* d_in, const int* in_sizes, int n_in,
                              void* d_out, int out_size, void* d_ws, size_t ws_size,
                              hipStream_t stream) {
  const float* xf  = (const float*)d_in[0];  // (1, N, 128)
  const float* up  = (const float*)d_in[1];  // (1, 7, M, K)  == [7][PP]
  const int*   idx = (const int*)d_in[2];    // (1, M, K)
  const float* w0  = (const float*)d_in[3];  // (128, 7)
  const float* wc  = (const float*)d_in[4];  // (7, 128, 128)
  const float* gam = (const float*)d_in[5];  // (8, 128)
  const float* bet = (const float*)d_in[6];  // (8, 128)
  const float* fw  = (const float*)d_in[7];  // (1, 128)
  const float* fb  = (const float*)d_in[8];  // (1,)
  float* out = (float*)d_out;

  char* ws = (char*)d_ws;
  const size_t zb     = (size_t)NT64 * 8192 * sizeof(h16); // frag-slot z
  const size_t statsb = 8 * 256 * sizeof(double);
  const size_t logb   = (size_t)PP * sizeof(float);
  const int NB = 1024;
  const int NBL = 768;   // k_layer: 3 blocks/CU x 256 CUs
  const int nbo = (MM + 3) / 4;

  if (ws_size >= zb + statsb + logb) {
    // Fast path: frag-slot fp16 z + block-cooperative MFMA layers.
    h16* z = (h16*)ws;
    double* gs = (double*)(ws + zb);
    float* logits = (float*)(ws + zb + statsb);

    k_zero<<<1, 256, 0, stream>>>(gs);
    k_layer0<<<dim3(NB, 4), 256, 0, stream>>>(up, w0, z, gs);
    for (int i = 1; i <= 7; ++i) {
      k_layer<<<NBL, 256, 0, stream>>>(z,
                                       gs + (size_t)(i - 1) * 256,
                                       gs + (size_t)i * 256,
                                       wc + (size_t)(i - 1) * 128 * 128,
                                       gam + (size_t)(i - 1) * 128,
                                       bet + (size_t)(i - 1) * 128);
    }
    k_logits<<<2048, 256, 0, stream>>>(z, gs + 7 * 256, gam + 7 * 128,
                                       bet + 7 * 128, fw, fb, logits);
    k_out<<<nbo, 256, 0, stream>>>(logits, idx, xf, out);
  } else {
    // Fallback: recompute chain, needs only ~2.9 MiB of workspace.
    double* gs = (double*)ws;
    float* logits = (float*)(ws + statsb);

    k_zero<<<1, 256, 0, stream>>>(gs);
    for (int j = 0; j <= 7; ++j) {
      k_chain<<<NB, 256, 0, stream>>>(up, w0, wc, gam, bet, gs,
                                      gs + (size_t)j * 256, j, 0,
                                      fw, fb, logits);
    }
    k_chain<<<NB, 256, 0, stream>>>(up, w0, wc, gam, bet, gs,
                                    nullptr, 7, 1, fw, fb, logits);
    k_out<<<nbo, 256, 0, stream>>>(logits, idx, xf, out);
  }
}